// Round 16
// baseline (2568.083 us; speedup 1.0000x reference)
//
#include <hip/hip_runtime.h>

namespace {

constexpr int Bb = 512, Tt = 512, Ff = 64, Hh = 128, Gg = 384;
constexpr int CH = 64;            // time-chunk length
constexpr int NCH = Tt / CH;      // 8 chunks

using short8  = __attribute__((ext_vector_type(8))) short;
using short4v = __attribute__((ext_vector_type(4))) short;
using f32x4   = __attribute__((ext_vector_type(4))) float;

__device__ __forceinline__ short f2bf(float f) {
  unsigned u = __float_as_uint(f);
  u += 0x7FFFu + ((u >> 16) & 1u);   // round-to-nearest-even
  return (short)(u >> 16);
}
__device__ __forceinline__ float bf2f(short s) {
  return __uint_as_float(((unsigned)(unsigned short)s) << 16);
}
__device__ __forceinline__ float sigm(float x) { return 1.0f / (1.0f + __expf(-x)); }
__device__ __forceinline__ float tanh_fast(float x) { return 1.0f - 2.0f / (1.0f + __expf(2.0f * x)); }

__device__ __forceinline__ void gl_lds16(const char* g, char* l) {
  __builtin_amdgcn_global_load_lds((const __attribute__((address_space(1))) void*)g,
                                   (__attribute__((address_space(3))) void*)l, 16, 0, 0);
}

// ---------------------------------------------------------------------------
// prep: gather fp32 weights into bf16 MFMA fragment images (16B per lane).
// ---------------------------------------------------------------------------
__global__ __launch_bounds__(512, 4) void prep(const float* __restrict__ Wx0,
                                               const float* __restrict__ Wxr,
                                               const float* __restrict__ Wh,
                                               const float* __restrict__ Wd,
                                               char* __restrict__ WhF,
                                               char* __restrict__ WxF,
                                               char* __restrict__ WdF) {
  const int id = blockIdx.x * 512 + threadIdx.x;
  const int lane = id & 63, lr = lane & 15, lk = lane >> 4;
  const int q = id >> 6;
  const float* src; int col, ldn, row0; char* dst;
  if (q < 288) {         // WhF
    const int l = q / 96, rem = q % 96, w = rem / 12, f = rem % 12;
    const int g = f >> 2, ks = f & 3;
    src = Wh + (size_t)l * Hh * Gg; ldn = Gg;
    col = g * 128 + w * 16 + lr; row0 = ks * 32 + lk * 8;
    dst = WhF + (size_t)(q * 64 + lane) * 16;
  } else if (q < 528) {  // WxF
    int p = q - 288; int base;
    if (p < 48)       { src = Wx0; base = 0; }
    else if (p < 144) { src = Wxr; base = 48; p -= 48; }
    else              { src = Wxr + (size_t)Hh * Gg; base = 144; p -= 144; }
    int ct, ks;
    if (base == 0) { ct = p >> 1; ks = p & 1; } else { ct = p >> 2; ks = p & 3; }
    ldn = Gg; col = ct * 16 + lr; row0 = ks * 32 + lk * 8;
    dst = WxF + (size_t)((base + p) * 64 + lane) * 16;
  } else {               // WdF
    const int p = q - 528;
    const int ct = p >> 2, ks = p & 3;
    src = Wd; ldn = Hh; col = ct * 16 + lr; row0 = ks * 32 + lk * 8;
    dst = WdF + (size_t)(p * 64 + lane) * 16;
  }
  short8 v;
#pragma unroll
  for (int j = 0; j < 8; ++j) v[j] = f2bf(src[(size_t)(row0 + j) * ldn + col]);
  *(short8*)dst = v;
}

// ---------------------------------------------------------------------------
// gx chunk GEMM (swapped operands) — unchanged from round 15.
// ---------------------------------------------------------------------------
template <int KS>
__device__ void gemm_chunk(const void* __restrict__ src, int t0,
                           const char* __restrict__ wxf,
                           const float* __restrict__ bias,
                           char* __restrict__ gx, int wg, char* at) {
  constexpr int ROWB = KS * 64;   // bytes per A row
  const int tid = threadIdx.x;
  const int w = tid >> 6, lane = tid & 63, lr = lane & 15, lk = lane >> 4;
  const int trel = wg >> 3, b0 = (wg & 7) * 64;

  if constexpr (KS == 2) {
    const float* x = (const float*)src;
    const int row = tid >> 3, seg = tid & 7;
    const float* pr = x + ((size_t)(b0 + row) * Tt + t0 + trel) * Ff + seg * 8;
    f32x4 a = *(const f32x4*)pr, c = *(const f32x4*)(pr + 4);
    short8 o;
#pragma unroll
    for (int j = 0; j < 4; ++j) { o[j] = f2bf(a[j]); o[4 + j] = f2bf(c[j]); }
    *(short8*)(at + row * ROWB + ((seg * 16) ^ ((row & 7) << 4))) = o;
  } else {
    const char* h = (const char*)src + ((size_t)trel * 512 + b0) * ROWB;
    gl_lds16(h + tid * 16, at + tid * 16);
    gl_lds16(h + 8192 + tid * 16, at + 8192 + tid * 16);
    asm volatile("s_waitcnt vmcnt(0)");
  }
  __syncthreads();

  short8 bw[3][KS];
  f32x4 bs4[3];
#pragma unroll
  for (int c = 0; c < 3; ++c) {
    const int ct = w * 3 + c;
    bs4[c] = *(const f32x4*)(bias + ct * 16 + lk * 4);
#pragma unroll
    for (int ks = 0; ks < KS; ++ks)
      bw[c][ks] = *(const short8*)(wxf + (size_t)((ct * KS + ks) * 64 + lane) * 16);
  }

#pragma unroll
  for (int rt = 0; rt < 4; ++rt) {
    const int row = rt * 16 + lr;
    short8 aa[KS];
#pragma unroll
    for (int ks = 0; ks < KS; ++ks)
      aa[ks] = *(const short8*)(at + row * ROWB + ((ks * 64 + lk * 16) ^ ((row & 7) << 4)));
#pragma unroll
    for (int c = 0; c < 3; ++c) {
      f32x4 acc = {0.f, 0.f, 0.f, 0.f};
#pragma unroll
      for (int ks = 0; ks < KS; ++ks)
        acc = __builtin_amdgcn_mfma_f32_16x16x32_bf16(bw[c][ks], aa[ks], acc, 0, 0, 0);
      const int ct = w * 3 + c;
      short4v o;
#pragma unroll
      for (int i = 0; i < 4; ++i) o[i] = f2bf(acc[i] + bs4[c][i]);
      const int rb = (b0 >> 4) + rt;
      *(short4v*)(gx + (size_t)((trel * 32 + rb) * 8 + (ct & 7)) * 1536 + lane * 24 + (ct >> 3) * 8) = o;
    }
  }
}

// ---------------------------------------------------------------------------
// GRU scan over one time chunk (swapped operands) — unchanged from round 15.
// ---------------------------------------------------------------------------
template <bool DENSE>
__device__ void scan_chunk(const char* __restrict__ gx,
                           const char* __restrict__ whf,
                           short* __restrict__ hstream,
                           float* __restrict__ state, int t0,
                           const char* __restrict__ wdf,
                           const float* __restrict__ bdp,
                           float* __restrict__ out, int rb,
                           char* h_buf, float* ob) {
  const int tid = threadIdx.x;
  const int w = tid >> 6, lane = tid & 63, lr = lane & 15, lk = lane >> 4;

  short8 bwh[3][4];
#pragma unroll
  for (int g = 0; g < 3; ++g)
#pragma unroll
    for (int ks = 0; ks < 4; ++ks)
      bwh[g][ks] = *(const short8*)(whf + (size_t)((w * 12 + g * 4 + ks) * 64 + lane) * 16);

  short8 bwd[4];
  f32x4 bd4 = {0.f, 0.f, 0.f, 0.f};
  if constexpr (DENSE) {
#pragma unroll
    for (int ks = 0; ks < 4; ++ks)
      bwd[ks] = *(const short8*)(wdf + (size_t)((w * 4 + ks) * 64 + lane) * 16);
    bd4 = *(const f32x4*)(bdp + w * 16 + lk * 4);
  }

  const int hoff = lr * 256 + (((w * 16 + lk * 4) * 2) ^ ((lr & 7) << 4));

  float hreg[4];
  if (t0 == 0) {
#pragma unroll
    for (int i = 0; i < 4; ++i) hreg[i] = 0.f;
    short* hz = (short*)h_buf;
    for (int i = tid; i < 2048; i += 512) hz[i] = 0;
  } else {
    f32x4 s = *(const f32x4*)(state + (size_t)(rb * 512 + tid) * 4);
    short4v sv;
#pragma unroll
    for (int i = 0; i < 4; ++i) { hreg[i] = s[i]; sv[i] = f2bf(s[i]); }
    *(short4v*)(h_buf + hoff) = sv;
  }

  auto issue = [&](int trel, short4v* d) {
    const char* p = gx + (size_t)((trel * 32 + rb) * 8 + w) * 1536 + lane * 24;
    d[0] = *(const short4v*)p;
    d[1] = *(const short4v*)(p + 8);
    d[2] = *(const short4v*)(p + 16);
  };
  short4v pfA[3], pfB[3];
  issue(0, pfA);
  issue(1, pfB);
  __syncthreads();

  auto step = [&](int t, short4v* cur) {
    const int pp = t & 1;
    char* const hsrc = h_buf + pp * 4096;
    char* const hdst = h_buf + (1 - pp) * 4096;

    const short4v g0 = cur[0], g1 = cur[1], g2 = cur[2];

    short8 ah[4];
#pragma unroll
    for (int ks = 0; ks < 4; ++ks)
      ah[ks] = *(const short8*)(hsrc + lr * 256 + ((ks * 64 + lk * 16) ^ ((lr & 7) << 4)));

    f32x4 aZ = {0.f, 0.f, 0.f, 0.f}, aR = aZ, aHn = aZ;
#pragma unroll
    for (int ks = 0; ks < 4; ++ks) {
      aZ  = __builtin_amdgcn_mfma_f32_16x16x32_bf16(bwh[0][ks], ah[ks], aZ, 0, 0, 0);
      aR  = __builtin_amdgcn_mfma_f32_16x16x32_bf16(bwh[1][ks], ah[ks], aR, 0, 0, 0);
      aHn = __builtin_amdgcn_mfma_f32_16x16x32_bf16(bwh[2][ks], ah[ks], aHn, 0, 0, 0);
    }
    if (t + 2 < t0 + CH) issue(t + 2 - t0, cur);

    if constexpr (DENSE) {
      if (t > 0) {
        f32x4 aD = {0.f, 0.f, 0.f, 0.f};
#pragma unroll
        for (int ks = 0; ks < 4; ++ks)
          aD = __builtin_amdgcn_mfma_f32_16x16x32_bf16(bwd[ks], ah[ks], aD, 0, 0, 0);
        f32x4 ov;
#pragma unroll
        for (int i = 0; i < 4; ++i) ov[i] = sigm(aD[i] + bd4[i]);
        *(f32x4*)(ob + pp * 2048 + lr * 128 + w * 16 + lk * 4) = ov;
      }
    }

    float hn4[4];
#pragma unroll
    for (int i = 0; i < 4; ++i) {
      const float z = sigm(aZ[i] + bf2f(g0[i]));
      const float r = sigm(aR[i] + bf2f(g1[i]));
      const float n = tanh_fast(bf2f(g2[i]) + r * aHn[i]);
      const float h = z * hreg[i] + (1.f - z) * n;
      hreg[i] = h;
      hn4[i] = h;
    }
    unsigned p01, p23;
    asm("v_cvt_pk_bf16_f32 %0, %1, %2" : "=v"(p01) : "v"(hn4[0]), "v"(hn4[1]));
    asm("v_cvt_pk_bf16_f32 %0, %1, %2" : "=v"(p23) : "v"(hn4[2]), "v"(hn4[3]));
    const unsigned long long hv64 = ((unsigned long long)p23 << 32) | p01;
    *(unsigned long long*)(hdst + hoff) = hv64;   // ONE ds_write_b64

    __builtin_amdgcn_sched_barrier(0);
    asm volatile("s_waitcnt lgkmcnt(0)");
    __builtin_amdgcn_s_barrier();
    __builtin_amdgcn_sched_barrier(0);

    if constexpr (DENSE) {
      if (t > 0) {
        f32x4 v = *(const f32x4*)(ob + pp * 2048 + tid * 4);
        *(f32x4*)(out + ((size_t)(rb * 16 + (tid >> 5)) * Tt + (t - 1)) * Hh + (tid & 31) * 4) = v;
      }
    } else {
      short4v hv = *(const short4v*)(hdst + tid * 8);
      *(short4v*)(hstream + (size_t)((t - t0) * 512 + rb * 16 + (tid >> 5)) * 128 + (tid & 31) * 4) = hv;
    }
  };

  for (int tb = t0; tb < t0 + CH; tb += 2) {
    step(tb, pfA);
    step(tb + 1, pfB);
  }

  {
    f32x4 sv;
#pragma unroll
    for (int i = 0; i < 4; ++i) sv[i] = hreg[i];
    *(f32x4*)(state + (size_t)(rb * 512 + tid) * 4) = sv;
  }

  if constexpr (DENSE) {
    if (t0 + CH == Tt) {
      short8 ah[4];
#pragma unroll
      for (int ks = 0; ks < 4; ++ks)
        ah[ks] = *(const short8*)(h_buf + lr * 256 + ((ks * 64 + lk * 16) ^ ((lr & 7) << 4)));
      f32x4 aD = {0.f, 0.f, 0.f, 0.f};
#pragma unroll
      for (int ks = 0; ks < 4; ++ks)
        aD = __builtin_amdgcn_mfma_f32_16x16x32_bf16(bwd[ks], ah[ks], aD, 0, 0, 0);
      f32x4 ov;
#pragma unroll
      for (int i = 0; i < 4; ++i) ov[i] = sigm(aD[i] + bd4[i]);
      *(f32x4*)(out + ((size_t)(rb * 16 + lr) * Tt + (Tt - 1)) * Hh + w * 16 + lk * 4) = ov;
    }
  }
}

struct GArgs { const void* src; char* gx; const char* wxf; const float* bias; int t0; int isx; };
struct SArgs { const char* gx; short* hstream; float* state; const char* whf; int t0; int dense; };

__global__ __launch_bounds__(512, 1) void gemm_multi(GArgs a0, GArgs a1, GArgs a2) {
  __shared__ char at[16384];
  const int g = blockIdx.x >> 9;
  const int wg = blockIdx.x & 511;
  GArgs a = (g == 0) ? a0 : (g == 1 ? a1 : a2);
  if (a.isx) gemm_chunk<2>(a.src, a.t0, a.wxf, a.bias, a.gx, wg, at);
  else       gemm_chunk<4>(a.src, a.t0, a.wxf, a.bias, a.gx, wg, at);
}

__global__ __launch_bounds__(512, 1) void scan_multi(SArgs a0, SArgs a1, SArgs a2,
                                                     const char* __restrict__ wdf,
                                                     const float* __restrict__ bd,
                                                     float* __restrict__ out) {
  __shared__ char hb[8192];
  __shared__ float ob[4096];
  const int g = blockIdx.x >> 5;
  const int rb = blockIdx.x & 31;
  SArgs a = (g == 0) ? a0 : (g == 1 ? a1 : a2);
  if (a.dense) scan_chunk<true >(a.gx, a.whf, a.hstream, a.state, a.t0, wdf, bd, out, rb, hb, ob);
  else         scan_chunk<false>(a.gx, a.whf, a.hstream, a.state, a.t0, wdf, bd, out, rb, hb, ob);
}

// ---------------------------------------------------------------------------
// DIAGNOSTIC PROBES (write only to ws scratch; d_out untouched).
// Replicate the scan step skeleton at matched occupancy (32 WGs x 512 thr).
// MODE 0 full: global gx loads + core {ds_read,MFMA,gate,ds_write} + sync + global store
// MODE 1 noglb: core + sync
// MODE 2 nosync: core only (LDS races are benign: dummy data, ws sink)
// MODE 3 min: LDS exchange (4x ds_read_b128 + ds_write_b64) + sync only
// ---------------------------------------------------------------------------
template <int MODE>
__device__ void probe_body(const char* __restrict__ gxsrc, char* __restrict__ sink,
                           float* __restrict__ keep, int nsteps) {
  __shared__ char hb[8192];
  const int tid = threadIdx.x;
  const int w = tid >> 6, lane = tid & 63, lr = lane & 15, lk = lane >> 4;

  short8 bwh[3][4];
#pragma unroll
  for (int g = 0; g < 3; ++g)
#pragma unroll
    for (int ks = 0; ks < 4; ++ks) {
      short8 v;
#pragma unroll
      for (int j = 0; j < 8; ++j)
        v[j] = f2bf(0.01f * (float)((lane + 3 * g + 5 * ks + j) & 15) - 0.07f);
      bwh[g][ks] = v;
    }

  const int hoff = lr * 256 + (((w * 16 + lk * 4) * 2) ^ ((lr & 7) << 4));
  {
    short* hz = (short*)hb;
    for (int i = tid; i < 4096; i += 512) hz[i] = 0;
  }
  float hreg[4] = {0.f, 0.f, 0.f, 0.f};
  short4v g0 = {0, 0, 0, 0}, g1 = g0, g2 = g0;
  __syncthreads();

  for (int t = 0; t < nsteps; ++t) {
    const int pp = t & 1;
    const char* hsrc = hb + pp * 4096;
    char* const hdst = hb + (1 - pp) * 4096;

    if (MODE == 0) {   // per-step global gx load, exact real addressing
      const char* p = gxsrc + (size_t)(((t & 63) * 32 + (blockIdx.x & 31)) * 8 + w) * 1536 + lane * 24;
      g0 = *(const short4v*)p;
      g1 = *(const short4v*)(p + 8);
      g2 = *(const short4v*)(p + 16);
    }

    if (MODE <= 2) {   // core: ds_read + MFMA chains + gating + ds_write
      short8 ah[4];
#pragma unroll
      for (int ks = 0; ks < 4; ++ks)
        ah[ks] = *(const short8*)(hsrc + lr * 256 + ((ks * 64 + lk * 16) ^ ((lr & 7) << 4)));
      f32x4 aZ = {0.f, 0.f, 0.f, 0.f}, aR = aZ, aHn = aZ;
#pragma unroll
      for (int ks = 0; ks < 4; ++ks) {
        aZ  = __builtin_amdgcn_mfma_f32_16x16x32_bf16(bwh[0][ks], ah[ks], aZ, 0, 0, 0);
        aR  = __builtin_amdgcn_mfma_f32_16x16x32_bf16(bwh[1][ks], ah[ks], aR, 0, 0, 0);
        aHn = __builtin_amdgcn_mfma_f32_16x16x32_bf16(bwh[2][ks], ah[ks], aHn, 0, 0, 0);
      }
      float hn4[4];
#pragma unroll
      for (int i = 0; i < 4; ++i) {
        const float z = sigm(aZ[i] + bf2f(g0[i]));
        const float r = sigm(aR[i] + bf2f(g1[i]));
        const float n = tanh_fast(bf2f(g2[i]) + r * aHn[i]);
        const float h = z * hreg[i] + (1.f - z) * n;
        hreg[i] = h;
        hn4[i] = h;
      }
      unsigned p01, p23;
      asm("v_cvt_pk_bf16_f32 %0, %1, %2" : "=v"(p01) : "v"(hn4[0]), "v"(hn4[1]));
      asm("v_cvt_pk_bf16_f32 %0, %1, %2" : "=v"(p23) : "v"(hn4[2]), "v"(hn4[3]));
      const unsigned long long hv64 = ((unsigned long long)p23 << 32) | p01;
      *(unsigned long long*)(hdst + hoff) = hv64;
    } else {           // minimal: exchange only
      short8 ah[4];
#pragma unroll
      for (int ks = 0; ks < 4; ++ks)
        ah[ks] = *(const short8*)(hsrc + lr * 256 + ((ks * 64 + lk * 16) ^ ((lr & 7) << 4)));
      asm volatile("" :: "v"(ah[0]), "v"(ah[1]), "v"(ah[2]), "v"(ah[3]));   // keep live
      hreg[0] += bf2f(ah[0][0]);
      const unsigned long long hv64 = 0x3f803f803f803f80ull ^ (unsigned long long)(t & 1);
      *(unsigned long long*)(hdst + hoff) = hv64;
    }

    if (MODE != 2) {   // the rendezvous: lgkm drain + s_barrier
      __builtin_amdgcn_sched_barrier(0);
      asm volatile("s_waitcnt lgkmcnt(0)");
      __builtin_amdgcn_s_barrier();
      __builtin_amdgcn_sched_barrier(0);
    } else {
      __builtin_amdgcn_sched_barrier(0);   // pin iteration order only
    }

    if (MODE == 0) {   // per-step global store, hstream-like coalescing
      short4v hv = *(const short4v*)(hdst + tid * 8);
      *(short4v*)(sink + (((size_t)(t & 63) * 512 + tid) * 8)) = hv;
    }
  }
  keep[(size_t)blockIdx.x * 512 + tid] = hreg[0] + hreg[1] + hreg[2] + hreg[3];
}

__global__ __launch_bounds__(512, 1) void probe_full(const char* gx, char* sink, float* keep, int n) {
  probe_body<0>(gx, sink, keep, n);
}
__global__ __launch_bounds__(512, 1) void probe_noglb(const char* gx, char* sink, float* keep, int n) {
  probe_body<1>(gx, sink, keep, n);
}
__global__ __launch_bounds__(512, 1) void probe_nosync(const char* gx, char* sink, float* keep, int n) {
  probe_body<2>(gx, sink, keep, n);
}
__global__ __launch_bounds__(512, 1) void probe_min(const char* gx, char* sink, float* keep, int n) {
  probe_body<3>(gx, sink, keep, n);
}

}  // namespace

extern "C" void kernel_launch(void* const* d_in, const int* in_sizes, int n_in,
                              void* d_out, int out_size, void* d_ws, size_t ws_size,
                              hipStream_t stream) {
  const float* x   = (const float*)d_in[0];   // [B,T,F]
  const float* Wx0 = (const float*)d_in[1];   // [F,3H]
  const float* Wxr = (const float*)d_in[2];   // [L-1,H,3H]
  const float* Wh  = (const float*)d_in[3];   // [L,H,3H]
  const float* b   = (const float*)d_in[4];   // [L,3H]
  const float* Wd  = (const float*)d_in[5];   // [H,H]
  const float* bd  = (const float*)d_in[6];   // [H]
  float* out = (float*)d_out;

  char* ws = (char*)d_ws;
  char*  WhF   = ws;                               // 294912 B
  char*  WxF   = ws + 294912;                      // 245760 B
  char*  WdF   = ws + 540672;                      // 32768 B
  float* state0 = (float*)(ws + 573440);           // 3 x 262144 B
  float* state1 = state0 + 65536;
  float* state2 = state1 + 65536;
  char*  gx0 = ws + 2097152;                       // 3 x 25165824 B
  char*  gx1 = gx0 + 25165824;
  char*  gx2 = gx1 + 25165824;
  char*  hc  = ws + 2097152 + 3 * 25165824;        // 4 x 8388608 B: [l][parity]

  prep<<<70, 512, 0, stream>>>(Wx0, Wxr, Wh, Wd, WhF, WxF, WdF);

  const size_t WXOFF[3] = {0, 49152, 147456};
  for (int r = 0; r < NCH + 2; ++r) {
    GArgs ga[3]; SArgs sa[3]; int n = 0;
    for (int l = 0; l < 3; ++l) {
      const int k = r - l;
      if (k < 0 || k >= NCH) continue;
      const void* src = (l == 0) ? (const void*)x
                                 : (const void*)(hc + ((size_t)((l - 1) * 2 + (k & 1))) * 8388608);
      char*  gxl = (l == 0) ? gx0 : (l == 1 ? gx1 : gx2);
      float* st  = (l == 0) ? state0 : (l == 1 ? state1 : state2);
      ga[n] = { src, gxl, WxF + WXOFF[l], b + l * Gg, k * CH, l == 0 };
      sa[n] = { gxl, (l < 2) ? (short*)(hc + (size_t)(l * 2 + (k & 1)) * 8388608) : (short*)nullptr,
                st, WhF + (size_t)l * 98304, k * CH, l == 2 };
      ++n;
    }
    for (int i = n; i < 3; ++i) { ga[i] = ga[0]; sa[i] = sa[0]; }
    gemm_multi<<<n * 512, 512, 0, stream>>>(ga[0], ga[1], ga[2]);
    scan_multi<<<n * 32, 512, 0, stream>>>(sa[0], sa[1], sa[2], WdF, bd, out);
  }

  // diagnostic probes (scratch-only; removed next round)
  char*  psink = gx1;              // rewritten by gemm before any consumption next call
  float* pkeep = (float*)gx2;
  probe_full  <<<32, 512, 0, stream>>>(gx0, psink, pkeep, 256);
  probe_noglb <<<32, 512, 0, stream>>>(gx0, psink, pkeep, 384);
  probe_nosync<<<32, 512, 0, stream>>>(gx0, psink, pkeep, 512);
  probe_min   <<<32, 512, 0, stream>>>(gx0, psink, pkeep, 1024);
}

// Round 17
// 1979.066 us; speedup vs baseline: 1.2976x; 1.2976x over previous
//
#include <hip/hip_runtime.h>

namespace {

constexpr int Bb = 512, Tt = 512, Ff = 64, Hh = 128, Gg = 384;
constexpr int CH = 64;            // time-chunk length
constexpr int NCH = Tt / CH;      // 8 chunks

using short8  = __attribute__((ext_vector_type(8))) short;
using short4v = __attribute__((ext_vector_type(4))) short;
using f32x4   = __attribute__((ext_vector_type(4))) float;

__device__ __forceinline__ short f2bf(float f) {
  unsigned u = __float_as_uint(f);
  u += 0x7FFFu + ((u >> 16) & 1u);   // round-to-nearest-even
  return (short)(u >> 16);
}
__device__ __forceinline__ float bf2f(short s) {
  return __uint_as_float(((unsigned)(unsigned short)s) << 16);
}
__device__ __forceinline__ float sigm(float x) { return 1.0f / (1.0f + __expf(-x)); }
__device__ __forceinline__ float tanh_fast(float x) { return 1.0f - 2.0f / (1.0f + __expf(2.0f * x)); }

__device__ __forceinline__ void gl_lds16(const char* g, char* l) {
  __builtin_amdgcn_global_load_lds((const __attribute__((address_space(1))) void*)g,
                                   (__attribute__((address_space(3))) void*)l, 16, 0, 0);
}

// ---------------------------------------------------------------------------
// prep: gather fp32 weights into bf16 MFMA fragment images (16B per lane).
// ---------------------------------------------------------------------------
__global__ __launch_bounds__(512, 4) void prep(const float* __restrict__ Wx0,
                                               const float* __restrict__ Wxr,
                                               const float* __restrict__ Wh,
                                               const float* __restrict__ Wd,
                                               char* __restrict__ WhF,
                                               char* __restrict__ WxF,
                                               char* __restrict__ WdF) {
  const int id = blockIdx.x * 512 + threadIdx.x;
  const int lane = id & 63, lr = lane & 15, lk = lane >> 4;
  const int q = id >> 6;
  const float* src; int col, ldn, row0; char* dst;
  if (q < 288) {         // WhF
    const int l = q / 96, rem = q % 96, w = rem / 12, f = rem % 12;
    const int g = f >> 2, ks = f & 3;
    src = Wh + (size_t)l * Hh * Gg; ldn = Gg;
    col = g * 128 + w * 16 + lr; row0 = ks * 32 + lk * 8;
    dst = WhF + (size_t)(q * 64 + lane) * 16;
  } else if (q < 528) {  // WxF
    int p = q - 288; int base;
    if (p < 48)       { src = Wx0; base = 0; }
    else if (p < 144) { src = Wxr; base = 48; p -= 48; }
    else              { src = Wxr + (size_t)Hh * Gg; base = 144; p -= 144; }
    int ct, ks;
    if (base == 0) { ct = p >> 1; ks = p & 1; } else { ct = p >> 2; ks = p & 3; }
    ldn = Gg; col = ct * 16 + lr; row0 = ks * 32 + lk * 8;
    dst = WxF + (size_t)((base + p) * 64 + lane) * 16;
  } else {               // WdF
    const int p = q - 528;
    const int ct = p >> 2, ks = p & 3;
    src = Wd; ldn = Hh; col = ct * 16 + lr; row0 = ks * 32 + lk * 8;
    dst = WdF + (size_t)(p * 64 + lane) * 16;
  }
  short8 v;
#pragma unroll
  for (int j = 0; j < 8; ++j) v[j] = f2bf(src[(size_t)(row0 + j) * ldn + col]);
  *(short8*)dst = v;
}

// ---------------------------------------------------------------------------
// gx chunk GEMM (swapped operands) — unchanged from round 15.
// ---------------------------------------------------------------------------
template <int KS>
__device__ void gemm_chunk(const void* __restrict__ src, int t0,
                           const char* __restrict__ wxf,
                           const float* __restrict__ bias,
                           char* __restrict__ gx, int wg, char* at) {
  constexpr int ROWB = KS * 64;   // bytes per A row
  const int tid = threadIdx.x;
  const int w = tid >> 6, lane = tid & 63, lr = lane & 15, lk = lane >> 4;
  const int trel = wg >> 3, b0 = (wg & 7) * 64;

  if constexpr (KS == 2) {
    const float* x = (const float*)src;
    const int row = tid >> 3, seg = tid & 7;
    const float* pr = x + ((size_t)(b0 + row) * Tt + t0 + trel) * Ff + seg * 8;
    f32x4 a = *(const f32x4*)pr, c = *(const f32x4*)(pr + 4);
    short8 o;
#pragma unroll
    for (int j = 0; j < 4; ++j) { o[j] = f2bf(a[j]); o[4 + j] = f2bf(c[j]); }
    *(short8*)(at + row * ROWB + ((seg * 16) ^ ((row & 7) << 4))) = o;
  } else {
    const char* h = (const char*)src + ((size_t)trel * 512 + b0) * ROWB;
    gl_lds16(h + tid * 16, at + tid * 16);
    gl_lds16(h + 8192 + tid * 16, at + 8192 + tid * 16);
    asm volatile("s_waitcnt vmcnt(0)");
  }
  __syncthreads();

  short8 bw[3][KS];
  f32x4 bs4[3];
#pragma unroll
  for (int c = 0; c < 3; ++c) {
    const int ct = w * 3 + c;
    bs4[c] = *(const f32x4*)(bias + ct * 16 + lk * 4);
#pragma unroll
    for (int ks = 0; ks < KS; ++ks)
      bw[c][ks] = *(const short8*)(wxf + (size_t)((ct * KS + ks) * 64 + lane) * 16);
  }

#pragma unroll
  for (int rt = 0; rt < 4; ++rt) {
    const int row = rt * 16 + lr;
    short8 aa[KS];
#pragma unroll
    for (int ks = 0; ks < KS; ++ks)
      aa[ks] = *(const short8*)(at + row * ROWB + ((ks * 64 + lk * 16) ^ ((row & 7) << 4)));
#pragma unroll
    for (int c = 0; c < 3; ++c) {
      f32x4 acc = {0.f, 0.f, 0.f, 0.f};
#pragma unroll
      for (int ks = 0; ks < KS; ++ks)
        acc = __builtin_amdgcn_mfma_f32_16x16x32_bf16(bw[c][ks], aa[ks], acc, 0, 0, 0);
      const int ct = w * 3 + c;
      short4v o;
#pragma unroll
      for (int i = 0; i < 4; ++i) o[i] = f2bf(acc[i] + bs4[c][i]);
      const int rb = (b0 >> 4) + rt;
      *(short4v*)(gx + (size_t)((trel * 32 + rb) * 8 + (ct & 7)) * 1536 + lane * 24 + (ct >> 3) * 8) = o;
    }
  }
}

// ---------------------------------------------------------------------------
// DUAL GRU scan: one WG = TWO batch-blocks (rb0, rb1), both recurrences
// interleaved in each wave's instruction stream; per-recurrence LDS flag
// sync (R12 protocol, verified) instead of s_barrier so the two chains can
// drift. B's issue fills A's latency stalls (probe: chain is latency-bound).
// ---------------------------------------------------------------------------
template <bool DENSE>
__device__ void scan_dual(const char* __restrict__ gx,
                          const char* __restrict__ whf,
                          short* __restrict__ hstream,
                          float* __restrict__ state, int t0,
                          const char* __restrict__ wdf,
                          const float* __restrict__ bdp,
                          float* __restrict__ out, int pb,
                          char* hbA, char* hbB, int* cntA, int* cntB) {
  const int tid = threadIdx.x;
  const int w = tid >> 6, lane = tid & 63, lr = lane & 15, lk = lane >> 4;
  const int rb0 = pb * 2, rb1 = pb * 2 + 1;

  short8 bwh[3][4];
#pragma unroll
  for (int g = 0; g < 3; ++g)
#pragma unroll
    for (int ks = 0; ks < 4; ++ks)
      bwh[g][ks] = *(const short8*)(whf + (size_t)((w * 12 + g * 4 + ks) * 64 + lane) * 16);

  short8 bwd[4];
  f32x4 bd4 = {0.f, 0.f, 0.f, 0.f};
  if constexpr (DENSE) {
#pragma unroll
    for (int ks = 0; ks < 4; ++ks)
      bwd[ks] = *(const short8*)(wdf + (size_t)((w * 4 + ks) * 64 + lane) * 16);
    bd4 = *(const f32x4*)(bdp + w * 16 + lk * 4);
  }

  const int hoff = lr * 256 + (((w * 16 + lk * 4) * 2) ^ ((lr & 7) << 4));

  if (tid == 0) { *cntA = 0; *cntB = 0; }

  float hrA[4], hrB[4];
  if (t0 == 0) {
#pragma unroll
    for (int i = 0; i < 4; ++i) { hrA[i] = 0.f; hrB[i] = 0.f; }
    short* za = (short*)hbA;
    short* zb = (short*)hbB;
    for (int i = tid; i < 2048; i += 512) { za[i] = 0; zb[i] = 0; }
  } else {
    f32x4 sA = *(const f32x4*)(state + (size_t)(rb0 * 512 + tid) * 4);
    f32x4 sB = *(const f32x4*)(state + (size_t)(rb1 * 512 + tid) * 4);
    short4v va, vb;
#pragma unroll
    for (int i = 0; i < 4; ++i) { hrA[i] = sA[i]; va[i] = f2bf(sA[i]);
                                  hrB[i] = sB[i]; vb[i] = f2bf(sB[i]); }
    *(short4v*)(hbA + hoff) = va;
    *(short4v*)(hbB + hoff) = vb;
  }

  auto issue = [&](int rb, int trel, short4v* d) {
    const char* p = gx + (size_t)((trel * 32 + rb) * 8 + w) * 1536 + lane * 24;
    d[0] = *(const short4v*)p;
    d[1] = *(const short4v*)(p + 8);
    d[2] = *(const short4v*)(p + 16);
  };
  short4v qA0[3], qA1[3], qB0[3], qB1[3];
  issue(rb0, 0, qA0); issue(rb0, 1, qA1);
  issue(rb1, 0, qB0); issue(rb1, 1, qB1);
  __syncthreads();   // prologue only: h(0)/state + cnt=0 visible

  auto WAITP = [&](int* c, int target) {
    int budget = 1 << 22;   // bail (visible wrong result) instead of hang
    while (__hip_atomic_load(c, __ATOMIC_RELAXED, __HIP_MEMORY_SCOPE_WORKGROUP) < target &&
           --budget) {}
  };

  auto DUAL = [&](int t, short4v (&qA)[3], short4v (&qB)[3]) {
    const int pin = t & 1;
    const char* hsA = hbA + pin * 4096;
    char* const hdA = hbA + (1 - pin) * 4096;
    const char* hsB = hbB + pin * 4096;
    char* const hdB = hbB + (1 - pin) * 4096;
    const int tg = t0 + t;

    if (t > 0) { WAITP(cntA, 8 * t); WAITP(cntB, 8 * t); }
    __builtin_amdgcn_sched_barrier(0);   // no ds_read hoisted above the polls

    if (!DENSE && t > 0) {   // stream h(t-1), both recurrences (fire-and-forget)
      short4v ha = *(const short4v*)(hsA + tid * 8);
      short4v hb = *(const short4v*)(hsB + tid * 8);
      *(short4v*)(hstream + ((size_t)(t - 1) * 512 + rb0 * 16 + (tid >> 5)) * 128 + (tid & 31) * 4) = ha;
      *(short4v*)(hstream + ((size_t)(t - 1) * 512 + rb1 * 16 + (tid >> 5)) * 128 + (tid & 31) * 4) = hb;
    }

    // snapshot gx before refill
    const short4v a0 = qA[0], a1 = qA[1], a2 = qA[2];
    const short4v b0 = qB[0], b1 = qB[1], b2 = qB[2];

    short8 ahA[4], ahB[4];
#pragma unroll
    for (int ks = 0; ks < 4; ++ks) {
      const int off = lr * 256 + ((ks * 64 + lk * 16) ^ ((lr & 7) << 4));
      ahA[ks] = *(const short8*)(hsA + off);
      ahB[ks] = *(const short8*)(hsB + off);
    }
    if (t + 2 < CH) { issue(rb0, t + 2, qA); issue(rb1, t + 2, qB); }

    f32x4 zA = {0.f, 0.f, 0.f, 0.f}, rA = zA, nA = zA;
    f32x4 zB = zA, rB = zA, nB = zA;
#pragma unroll
    for (int ks = 0; ks < 4; ++ks) {
      zA = __builtin_amdgcn_mfma_f32_16x16x32_bf16(bwh[0][ks], ahA[ks], zA, 0, 0, 0);
      zB = __builtin_amdgcn_mfma_f32_16x16x32_bf16(bwh[0][ks], ahB[ks], zB, 0, 0, 0);
      rA = __builtin_amdgcn_mfma_f32_16x16x32_bf16(bwh[1][ks], ahA[ks], rA, 0, 0, 0);
      rB = __builtin_amdgcn_mfma_f32_16x16x32_bf16(bwh[1][ks], ahB[ks], rB, 0, 0, 0);
      nA = __builtin_amdgcn_mfma_f32_16x16x32_bf16(bwh[2][ks], ahA[ks], nA, 0, 0, 0);
      nB = __builtin_amdgcn_mfma_f32_16x16x32_bf16(bwh[2][ks], ahB[ks], nB, 0, 0, 0);
    }

    if constexpr (DENSE) {
      if (tg > 0) {   // direct fire-and-forget stores (no staging barrier now)
        f32x4 dA = {0.f, 0.f, 0.f, 0.f}, dB = dA;
#pragma unroll
        for (int ks = 0; ks < 4; ++ks) {
          dA = __builtin_amdgcn_mfma_f32_16x16x32_bf16(bwd[ks], ahA[ks], dA, 0, 0, 0);
          dB = __builtin_amdgcn_mfma_f32_16x16x32_bf16(bwd[ks], ahB[ks], dB, 0, 0, 0);
        }
        f32x4 oA, oB;
#pragma unroll
        for (int i = 0; i < 4; ++i) { oA[i] = sigm(dA[i] + bd4[i]); oB[i] = sigm(dB[i] + bd4[i]); }
        *(f32x4*)(out + ((size_t)(rb0 * 16 + lr) * Tt + (tg - 1)) * Hh + w * 16 + lk * 4) = oA;
        *(f32x4*)(out + ((size_t)(rb1 * 16 + lr) * Tt + (tg - 1)) * Hh + w * 16 + lk * 4) = oB;
      }
    }

    float hnA[4], hnB[4];
#pragma unroll
    for (int i = 0; i < 4; ++i) {
      {
        const float z = sigm(zA[i] + bf2f(a0[i]));
        const float r = sigm(rA[i] + bf2f(a1[i]));
        const float n = tanh_fast(bf2f(a2[i]) + r * nA[i]);
        const float h = z * hrA[i] + (1.f - z) * n;
        hrA[i] = h; hnA[i] = h;
      }
      {
        const float z = sigm(zB[i] + bf2f(b0[i]));
        const float r = sigm(rB[i] + bf2f(b1[i]));
        const float n = tanh_fast(bf2f(b2[i]) + r * nB[i]);
        const float h = z * hrB[i] + (1.f - z) * n;
        hrB[i] = h; hnB[i] = h;
      }
    }
    unsigned pa01, pa23, pb01, pb23;
    asm("v_cvt_pk_bf16_f32 %0, %1, %2" : "=v"(pa01) : "v"(hnA[0]), "v"(hnA[1]));
    asm("v_cvt_pk_bf16_f32 %0, %1, %2" : "=v"(pa23) : "v"(hnA[2]), "v"(hnA[3]));
    asm("v_cvt_pk_bf16_f32 %0, %1, %2" : "=v"(pb01) : "v"(hnB[0]), "v"(hnB[1]));
    asm("v_cvt_pk_bf16_f32 %0, %1, %2" : "=v"(pb23) : "v"(hnB[2]), "v"(hnB[3]));
    *(unsigned long long*)(hdA + hoff) = ((unsigned long long)pa23 << 32) | pa01;
    *(unsigned long long*)(hdB + hoff) = ((unsigned long long)pb23 << 32) | pb01;

    // publish both: drain this wave's LDS ops, then one flag add per wave each
    __builtin_amdgcn_sched_barrier(0);
    asm volatile("s_waitcnt lgkmcnt(0)");
    __builtin_amdgcn_sched_barrier(0);
    if (lane == 0) { atomicAdd(cntA, 1); atomicAdd(cntB, 1); }
    __builtin_amdgcn_sched_barrier(0);
  };

  for (int tb = 0; tb < CH; tb += 2) {
    DUAL(tb, qA0, qB0);
    DUAL(tb + 1, qA1, qB1);
  }

  WAITP(cntA, 8 * CH);
  WAITP(cntB, 8 * CH);
  __builtin_amdgcn_sched_barrier(0);

  {  // save recurrent state for next chunk
    f32x4 sA, sB;
#pragma unroll
    for (int i = 0; i < 4; ++i) { sA[i] = hrA[i]; sB[i] = hrB[i]; }
    *(f32x4*)(state + (size_t)(rb0 * 512 + tid) * 4) = sA;
    *(f32x4*)(state + (size_t)(rb1 * 512 + tid) * 4) = sB;
  }

  if constexpr (!DENSE) {   // h(CH-1) sits in parity-0 buffers (CH even)
    short4v ha = *(const short4v*)(hbA + tid * 8);
    short4v hb = *(const short4v*)(hbB + tid * 8);
    *(short4v*)(hstream + ((size_t)(CH - 1) * 512 + rb0 * 16 + (tid >> 5)) * 128 + (tid & 31) * 4) = ha;
    *(short4v*)(hstream + ((size_t)(CH - 1) * 512 + rb1 * 16 + (tid >> 5)) * 128 + (tid & 31) * 4) = hb;
  } else if (t0 + CH == Tt) {   // final output row Tt-1
    short8 ahA[4], ahB[4];
#pragma unroll
    for (int ks = 0; ks < 4; ++ks) {
      const int off = lr * 256 + ((ks * 64 + lk * 16) ^ ((lr & 7) << 4));
      ahA[ks] = *(const short8*)(hbA + off);
      ahB[ks] = *(const short8*)(hbB + off);
    }
    f32x4 dA = {0.f, 0.f, 0.f, 0.f}, dB = dA;
#pragma unroll
    for (int ks = 0; ks < 4; ++ks) {
      dA = __builtin_amdgcn_mfma_f32_16x16x32_bf16(bwd[ks], ahA[ks], dA, 0, 0, 0);
      dB = __builtin_amdgcn_mfma_f32_16x16x32_bf16(bwd[ks], ahB[ks], dB, 0, 0, 0);
    }
    f32x4 oA, oB;
#pragma unroll
    for (int i = 0; i < 4; ++i) { oA[i] = sigm(dA[i] + bd4[i]); oB[i] = sigm(dB[i] + bd4[i]); }
    *(f32x4*)(out + ((size_t)(rb0 * 16 + lr) * Tt + (Tt - 1)) * Hh + w * 16 + lk * 4) = oA;
    *(f32x4*)(out + ((size_t)(rb1 * 16 + lr) * Tt + (Tt - 1)) * Hh + w * 16 + lk * 4) = oB;
  }
}

struct GArgs { const void* src; char* gx; const char* wxf; const float* bias; int t0; int isx; };
struct SArgs { const char* gx; short* hstream; float* state; const char* whf; int t0; int dense; };

__global__ __launch_bounds__(512, 1) void gemm_multi(GArgs a0, GArgs a1, GArgs a2) {
  __shared__ char at[16384];
  const int g = blockIdx.x >> 9;
  const int wg = blockIdx.x & 511;
  GArgs a = (g == 0) ? a0 : (g == 1 ? a1 : a2);
  if (a.isx) gemm_chunk<2>(a.src, a.t0, a.wxf, a.bias, a.gx, wg, at);
  else       gemm_chunk<4>(a.src, a.t0, a.wxf, a.bias, a.gx, wg, at);
}

__global__ __launch_bounds__(512, 1) void scan_multi(SArgs a0, SArgs a1, SArgs a2,
                                                     const char* __restrict__ wdf,
                                                     const float* __restrict__ bd,
                                                     float* __restrict__ out) {
  __shared__ char hbA[8192], hbB[8192];
  __shared__ int  cnt[2][16];   // 64B-strided counters
  const int g = blockIdx.x >> 4;
  const int pb = blockIdx.x & 15;
  SArgs a = (g == 0) ? a0 : (g == 1 ? a1 : a2);
  if (a.dense) scan_dual<true >(a.gx, a.whf, a.hstream, a.state, a.t0, wdf, bd, out,
                                pb, hbA, hbB, &cnt[0][0], &cnt[1][0]);
  else         scan_dual<false>(a.gx, a.whf, a.hstream, a.state, a.t0, wdf, bd, out,
                                pb, hbA, hbB, &cnt[0][0], &cnt[1][0]);
}

}  // namespace

extern "C" void kernel_launch(void* const* d_in, const int* in_sizes, int n_in,
                              void* d_out, int out_size, void* d_ws, size_t ws_size,
                              hipStream_t stream) {
  const float* x   = (const float*)d_in[0];   // [B,T,F]
  const float* Wx0 = (const float*)d_in[1];   // [F,3H]
  const float* Wxr = (const float*)d_in[2];   // [L-1,H,3H]
  const float* Wh  = (const float*)d_in[3];   // [L,H,3H]
  const float* b   = (const float*)d_in[4];   // [L,3H]
  const float* Wd  = (const float*)d_in[5];   // [H,H]
  const float* bd  = (const float*)d_in[6];   // [H]
  float* out = (float*)d_out;

  char* ws = (char*)d_ws;
  char*  WhF   = ws;                               // 294912 B
  char*  WxF   = ws + 294912;                      // 245760 B
  char*  WdF   = ws + 540672;                      // 32768 B
  float* state0 = (float*)(ws + 573440);           // 3 x 262144 B
  float* state1 = state0 + 65536;
  float* state2 = state1 + 65536;
  char*  gx0 = ws + 2097152;                       // 3 x 25165824 B
  char*  gx1 = gx0 + 25165824;
  char*  gx2 = gx1 + 25165824;
  char*  hc  = ws + 2097152 + 3 * 25165824;        // 4 x 8388608 B: [l][parity]

  prep<<<70, 512, 0, stream>>>(Wx0, Wxr, Wh, Wd, WhF, WxF, WdF);

  const size_t WXOFF[3] = {0, 49152, 147456};
  for (int r = 0; r < NCH + 2; ++r) {
    GArgs ga[3]; SArgs sa[3]; int n = 0;
    for (int l = 0; l < 3; ++l) {
      const int k = r - l;
      if (k < 0 || k >= NCH) continue;
      const void* src = (l == 0) ? (const void*)x
                                 : (const void*)(hc + ((size_t)((l - 1) * 2 + (k & 1))) * 8388608);
      char*  gxl = (l == 0) ? gx0 : (l == 1 ? gx1 : gx2);
      float* st  = (l == 0) ? state0 : (l == 1 ? state1 : state2);
      ga[n] = { src, gxl, WxF + WXOFF[l], b + l * Gg, k * CH, l == 0 };
      sa[n] = { gxl, (l < 2) ? (short*)(hc + (size_t)(l * 2 + (k & 1)) * 8388608) : (short*)nullptr,
                st, WhF + (size_t)l * 98304, k * CH, l == 2 };
      ++n;
    }
    for (int i = n; i < 3; ++i) { ga[i] = ga[0]; sa[i] = sa[0]; }
    gemm_multi<<<n * 512, 512, 0, stream>>>(ga[0], ga[1], ga[2]);
    scan_multi<<<n * 16, 512, 0, stream>>>(sa[0], sa[1], sa[2], WdF, bd, out);
  }
}